// Round 2
// baseline (99.475 us; speedup 1.0000x reference)
//
#include <hip/hip_runtime.h>

// ARAP local step, round 5 (= round-4 resubmit; bench never ran).
// Theory: kernel is LATENCY-bound, not throughput-bound. 100k threads
// = 391 blocks = ~6 waves/CU (19% occupancy); aggregate VALU (~2us) and HBM
// (~2us) are tiny vs the 94us measured -> divergent-gather latency with no TLP
// to hide it. Fix: 4 lanes per vertex (400k threads, ~24 waves/CU). Each lane
// gathers 4 neighbors (8 divergent dwordx4 instead of 32 per lane), partial
// covariance, then a 2-step __shfl_xor butterfly gives every lane the full S.
// All 4 lanes run the verified Horn eigensolve redundantly (free at wave
// granularity: masking 3 lanes off saves zero issue slots) and split the 9
// output stores. Eigensolve numerics unchanged from the verified round-2
// kernel (shifted-PD 4x4, 16 symmetric squarings, absmax 3.9e-3).

__global__ __launch_bounds__(256)
void prepack_kernel(const float* __restrict__ xyz1,
                    const float* __restrict__ xyz2,
                    float4* __restrict__ pk,   // [B*N][2] float4
                    int total)
{
    int t = blockIdx.x * blockDim.x + threadIdx.x;
    if (t >= total) return;
    float4 a, c;
    a.x = xyz1[t * 3 + 0]; a.y = xyz1[t * 3 + 1]; a.z = xyz1[t * 3 + 2]; a.w = 0.f;
    c.x = xyz2[t * 3 + 0]; c.y = xyz2[t * 3 + 1]; c.z = xyz2[t * 3 + 2]; c.w = 0.f;
    pk[2 * (size_t)t + 0] = a;
    pk[2 * (size_t)t + 1] = c;
}

__global__ __launch_bounds__(256)
void arap_rot_kernel(const float4* __restrict__ pk,
                     const int*   __restrict__ nbr,
                     const int*   __restrict__ num,
                     const int*   __restrict__ acc,
                     const float* __restrict__ wgt,
                     float*       __restrict__ out,
                     int B, int N)
{
    int t = blockIdx.x * blockDim.x + threadIdx.x;
    int total4 = B * N * 4;
    if (t >= total4) return;
    int v = t >> 2;          // vertex slot (b*N + i)
    int u = t & 3;           // sub-lane within the 4-lane group
    int b = v / N;
    int i = v - b * N;

    // Issue all independent scalar/vector loads up front so their latencies
    // overlap (a0/cnt are per-group uniform; L1 serves the 4x replication).
    int a0  = acc[i];
    int cnt = num[i];

    const float4* base = pk + 2 * (size_t)b * N;

    float4 P1 = base[2 * i + 0];
    float4 P2 = base[2 * i + 1];
    float p1x = P1.x, p1y = P1.y, p1z = P1.z;
    float p2x = P2.x, p2y = P2.y, p2z = P2.z;

    float Sxx = 0.f, Sxy = 0.f, Sxz = 0.f;
    float Syx = 0.f, Syy = 0.f, Syz = 0.f;
    float Szx = 0.f, Szy = 0.f, Szz = 0.f;

    if (cnt == 16 && (a0 & 3) == 0) {
        // Fast path: lane u owns neighbors 4u..4u+3. Consecutive lanes load
        // consecutive int4/float4 -> fully coalesced 64B per group. 8
        // address-divergent dwordx4 gathers per lane (pairs share a 64B line).
        const int4*   nb4 = (const int4*)(nbr + a0);
        const float4* w4  = (const float4*)(wgt + a0);
        int4   jj = nb4[u];
        float4 ww = w4[u];
        int js[4] = {jj.x, jj.y, jj.z, jj.w};
        float ws[4] = {ww.x, ww.y, ww.z, ww.w};
#pragma unroll
        for (int q = 0; q < 4; ++q) {
            int j = js[q];
            float4 A = base[2 * j + 0];
            float4 C = base[2 * j + 1];
            float we = ws[q];
            float d1x = p1x - A.x, d1y = p1y - A.y, d1z = p1z - A.z;
            float d2x = p2x - C.x, d2y = p2y - C.y, d2z = p2z - C.z;
            float w1x = we * d1x, w1y = we * d1y, w1z = we * d1z;
            Sxx += w1x * d2x;  Sxy += w1x * d2y;  Sxz += w1x * d2z;
            Syx += w1y * d2x;  Syy += w1y * d2y;  Syz += w1y * d2z;
            Szx += w1z * d2x;  Szy += w1z * d2y;  Szz += w1z * d2z;
        }
    } else {
        // General path: lane u takes neighbors u, u+4, u+8, ...
        for (int k = u; k < cnt; k += 4) {
            int   e  = a0 + k;
            int   j  = nbr[e];
            float we = wgt[e];
            float4 A = base[2 * j + 0];
            float4 C = base[2 * j + 1];
            float d1x = p1x - A.x, d1y = p1y - A.y, d1z = p1z - A.z;
            float d2x = p2x - C.x, d2y = p2y - C.y, d2z = p2z - C.z;
            float w1x = we * d1x, w1y = we * d1y, w1z = we * d1z;
            Sxx += w1x * d2x;  Sxy += w1x * d2y;  Sxz += w1x * d2z;
            Syx += w1y * d2x;  Syy += w1y * d2y;  Syz += w1y * d2z;
            Szx += w1z * d2x;  Szy += w1z * d2y;  Szz += w1z * d2z;
        }
    }

    // 4-lane butterfly reduction: after xor-1 and xor-2 every lane holds the
    // full per-vertex covariance. Groups of 4 never straddle the launch
    // boundary (total4 % 4 == 0), so all shuffle partners are active.
#define RED4(x) x += __shfl_xor(x, 1); x += __shfl_xor(x, 2)
    RED4(Sxx); RED4(Sxy); RED4(Sxz);
    RED4(Syx); RED4(Syy); RED4(Syz);
    RED4(Szx); RED4(Szy); RED4(Szz);
#undef RED4

    // Horn's 4x4 symmetric matrix (q = [w,x,y,z] basis); maps d1 -> d2.
    float n00 =  Sxx + Syy + Szz;
    float n01 =  Syz - Szy;
    float n02 =  Szx - Sxz;
    float n03 =  Sxy - Syx;
    float n11 =  Sxx - Syy - Szz;
    float n12 =  Sxy + Syx;
    float n13 =  Szx + Sxz;
    float n22 = -Sxx + Syy - Szz;
    float n23 =  Syz + Szy;
    float n33 = -Sxx - Syy + Szz;

    // Shift: all |eig(N)| <= sqrt(3)*||S||_F < 2*||S||_F  => M = N+sI is PD,
    // top eigvec of M == Horn's quaternion.
    float fro2 = Sxx*Sxx + Sxy*Sxy + Sxz*Sxz
               + Syx*Syx + Syy*Syy + Syz*Syz
               + Szx*Szx + Szy*Szy + Szz*Szz;
    float s = 2.0f * sqrtf(fro2) + 1e-30f;

    float m00 = n00 + s, m01 = n01, m02 = n02, m03 = n03;
    float m11 = n11 + s, m12 = n12, m13 = n13;
    float m22 = n22 + s, m23 = n23;
    float m33 = n33 + s;

    {
        float inv = 1.0f / (m00 + m11 + m22 + m33);
        m00 *= inv; m01 *= inv; m02 *= inv; m03 *= inv;
        m11 *= inv; m12 *= inv; m13 *= inv;
        m22 *= inv; m23 *= inv; m33 *= inv;
    }

    // 16 symmetric squarings with trace renormalization: M^(2^16) -> c*v*v^T.
#pragma unroll
    for (int it = 0; it < 16; ++it) {
        float p00 = m00*m00 + m01*m01 + m02*m02 + m03*m03;
        float p01 = m00*m01 + m01*m11 + m02*m12 + m03*m13;
        float p02 = m00*m02 + m01*m12 + m02*m22 + m03*m23;
        float p03 = m00*m03 + m01*m13 + m02*m23 + m03*m33;
        float p11 = m01*m01 + m11*m11 + m12*m12 + m13*m13;
        float p12 = m01*m02 + m11*m12 + m12*m22 + m13*m23;
        float p13 = m01*m03 + m11*m13 + m12*m23 + m13*m33;
        float p22 = m02*m02 + m12*m12 + m22*m22 + m23*m23;
        float p23 = m02*m03 + m12*m13 + m22*m23 + m23*m33;
        float p33 = m03*m03 + m13*m13 + m23*m23 + m33*m33;
        float inv = 1.0f / (p00 + p11 + p22 + p33);
        m00 = p00 * inv; m01 = p01 * inv; m02 = p02 * inv; m03 = p03 * inv;
        m11 = p11 * inv; m12 = p12 * inv; m13 = p13 * inv;
        m22 = p22 * inv; m23 = p23 * inv;
        m33 = p33 * inv;
    }

    // Column with the largest diagonal entry == top eigenvector.
    float qw = m00, qx = m01, qy = m02, qz = m03, best = m00;
    {
        bool g = m11 > best;
        qw = g ? m01 : qw; qx = g ? m11 : qx; qy = g ? m12 : qy; qz = g ? m13 : qz;
        best = g ? m11 : best;
        g = m22 > best;
        qw = g ? m02 : qw; qx = g ? m12 : qx; qy = g ? m22 : qy; qz = g ? m23 : qz;
        best = g ? m22 : best;
        g = m33 > best;
        qw = g ? m03 : qw; qx = g ? m13 : qx; qy = g ? m23 : qy; qz = g ? m33 : qz;
    }
    {
        float inv = rsqrtf(qw*qw + qx*qx + qy*qy + qz*qz);
        qw *= inv; qx *= inv; qy *= inv; qz *= inv;
    }

    // Quaternion -> rotation matrix (R d1 ~= d2), row-major 3x3
    float xx = qx*qx, yy = qy*qy, zz = qz*qz;
    float xy = qx*qy, xz = qx*qz, yz = qy*qz;
    float wx = qw*qx, wy = qw*qy, wz = qw*qz;

    float o0 = 1.f - 2.f*(yy + zz);
    float o1 = 2.f*(xy - wz);
    float o2 = 2.f*(xz + wy);
    float o3 = 2.f*(xy + wz);
    float o4 = 1.f - 2.f*(xx + zz);
    float o5 = 2.f*(yz - wx);
    float o6 = 2.f*(xz - wy);
    float o7 = 2.f*(yz + wx);
    float o8 = 1.f - 2.f*(xx + yy);

    // Split the 9 stores across the 4 lanes (static-index selects, no
    // runtime-indexed array -> stays in registers, rule #20).
    float* op = out + (size_t)v * 9;
    float w0 = (u == 0) ? o0 : (u == 1) ? o1 : (u == 2) ? o2 : o3;
    float w1 = (u == 0) ? o4 : (u == 1) ? o5 : (u == 2) ? o6 : o7;
    op[u]     = w0;
    op[4 + u] = w1;
    if (u == 0) op[8] = o8;
}

extern "C" void kernel_launch(void* const* d_in, const int* in_sizes, int n_in,
                              void* d_out, int out_size, void* d_ws, size_t ws_size,
                              hipStream_t stream) {
    const float* xyz1 = (const float*)d_in[0];
    const float* xyz2 = (const float*)d_in[1];
    const int*   nbr  = (const int*)  d_in[2];
    const int*   num  = (const int*)  d_in[3];
    const int*   acc  = (const int*)  d_in[4];
    const float* wgt  = (const float*)d_in[5];
    float* out = (float*)d_out;

    int N = in_sizes[3];               // numNeighbors has N entries
    int B = in_sizes[0] / (N * 3);     // xyz1 is [B,N,3]
    int total = B * N;

    float4* pk = (float4*)d_ws;        // [total][2] float4 = 32B/vertex

    int block = 256;
    int grid1 = (total + block - 1) / block;
    prepack_kernel<<<grid1, block, 0, stream>>>(xyz1, xyz2, pk, total);

    int total4 = total * 4;
    int grid2 = (total4 + block - 1) / block;
    arap_rot_kernel<<<grid2, block, 0, stream>>>(pk, nbr, num, acc, wgt,
                                                 out, B, N);
}

// Round 3
// 98.536 us; speedup vs baseline: 1.0095x; 1.0095x over previous
//
#include <hip/hip_runtime.h>

// ARAP local step, round 6.
// Round-5 post-mortem: kernel passed at 99.5us but the rocprof top-5 is ALL
// harness fillBufferAligned dispatches (256 MiB @ ~44us each) — workspace
// poisoning. Our compute is <43.5us (below cutoff; arithmetic says ~10us).
// dur_us ~= 2x44us poison + ~10us compute. Experiment: eliminate ALL
// workspace use (drop prepack kernel, gather xyz1/xyz2 directly). If the
// 256-MiB poison is conditional on ws usage, dur_us collapses to ~25us;
// if not, we learn the floor is harness overhead.
// Gather cost: 6 divergent dwords/neighbor (vs 2 packed dwordx4) = ~3x
// address-processing, ~+5-10us hidden under VALU at 24 waves/CU.
// Structure otherwise unchanged from verified round-5 kernel (4 lanes per
// vertex, 2-step shfl_xor butterfly, shifted-PD Horn eigensolve with 16
// symmetric squarings; absmax 3.9e-3).

__global__ __launch_bounds__(256)
void arap_rot_kernel(const float* __restrict__ xyz1,
                     const float* __restrict__ xyz2,
                     const int*   __restrict__ nbr,
                     const int*   __restrict__ num,
                     const int*   __restrict__ acc,
                     const float* __restrict__ wgt,
                     float*       __restrict__ out,
                     int B, int N)
{
    int t = blockIdx.x * blockDim.x + threadIdx.x;
    int total4 = B * N * 4;
    if (t >= total4) return;
    int v = t >> 2;          // vertex slot (b*N + i)
    int u = t & 3;           // sub-lane within the 4-lane group
    int b = v / N;
    int i = v - b * N;

    // Per-group-uniform CSR metadata (L1 serves the 4x replication).
    int a0  = acc[i];
    int cnt = num[i];

    const float* x1 = xyz1 + (size_t)(3 * N) * b;
    const float* x2 = xyz2 + (size_t)(3 * N) * b;

    int i3 = 3 * i;
    float p1x = x1[i3 + 0], p1y = x1[i3 + 1], p1z = x1[i3 + 2];
    float p2x = x2[i3 + 0], p2y = x2[i3 + 1], p2z = x2[i3 + 2];

    float Sxx = 0.f, Sxy = 0.f, Sxz = 0.f;
    float Syx = 0.f, Syy = 0.f, Syz = 0.f;
    float Szx = 0.f, Szy = 0.f, Szz = 0.f;

    if (cnt == 16 && (a0 & 3) == 0) {
        // Fast path: lane u owns neighbors 4u..4u+3. Consecutive lanes load
        // consecutive int4/float4 -> fully coalesced 64B per group. Neighbor
        // coords gathered directly (6 divergent dwords per neighbor).
        const int4*   nb4 = (const int4*)(nbr + a0);
        const float4* w4  = (const float4*)(wgt + a0);
        int4   jj = nb4[u];
        float4 ww = w4[u];
        int js[4] = {jj.x, jj.y, jj.z, jj.w};
        float ws[4] = {ww.x, ww.y, ww.z, ww.w};
#pragma unroll
        for (int q = 0; q < 4; ++q) {
            int j3 = 3 * js[q];
            float ax = x1[j3 + 0], ay = x1[j3 + 1], az = x1[j3 + 2];
            float cx = x2[j3 + 0], cy = x2[j3 + 1], cz = x2[j3 + 2];
            float we = ws[q];
            float d1x = p1x - ax, d1y = p1y - ay, d1z = p1z - az;
            float d2x = p2x - cx, d2y = p2y - cy, d2z = p2z - cz;
            float w1x = we * d1x, w1y = we * d1y, w1z = we * d1z;
            Sxx += w1x * d2x;  Sxy += w1x * d2y;  Sxz += w1x * d2z;
            Syx += w1y * d2x;  Syy += w1y * d2y;  Syz += w1y * d2z;
            Szx += w1z * d2x;  Szy += w1z * d2y;  Szz += w1z * d2z;
        }
    } else {
        // General path: lane u takes neighbors u, u+4, u+8, ...
        for (int k = u; k < cnt; k += 4) {
            int   e  = a0 + k;
            int   j3 = 3 * nbr[e];
            float we = wgt[e];
            float ax = x1[j3 + 0], ay = x1[j3 + 1], az = x1[j3 + 2];
            float cx = x2[j3 + 0], cy = x2[j3 + 1], cz = x2[j3 + 2];
            float d1x = p1x - ax, d1y = p1y - ay, d1z = p1z - az;
            float d2x = p2x - cx, d2y = p2y - cy, d2z = p2z - cz;
            float w1x = we * d1x, w1y = we * d1y, w1z = we * d1z;
            Sxx += w1x * d2x;  Sxy += w1x * d2y;  Sxz += w1x * d2z;
            Syx += w1y * d2x;  Syy += w1y * d2y;  Syz += w1y * d2z;
            Szx += w1z * d2x;  Szy += w1z * d2y;  Szz += w1z * d2z;
        }
    }

    // 4-lane butterfly reduction: after xor-1 and xor-2 every lane holds the
    // full per-vertex covariance. Groups of 4 never straddle the launch
    // boundary (total4 % 4 == 0), so all shuffle partners are active.
#define RED4(x) x += __shfl_xor(x, 1); x += __shfl_xor(x, 2)
    RED4(Sxx); RED4(Sxy); RED4(Sxz);
    RED4(Syx); RED4(Syy); RED4(Syz);
    RED4(Szx); RED4(Szy); RED4(Szz);
#undef RED4

    // Horn's 4x4 symmetric matrix (q = [w,x,y,z] basis); maps d1 -> d2.
    float n00 =  Sxx + Syy + Szz;
    float n01 =  Syz - Szy;
    float n02 =  Szx - Sxz;
    float n03 =  Sxy - Syx;
    float n11 =  Sxx - Syy - Szz;
    float n12 =  Sxy + Syx;
    float n13 =  Szx + Sxz;
    float n22 = -Sxx + Syy - Szz;
    float n23 =  Syz + Szy;
    float n33 = -Sxx - Syy + Szz;

    // Shift: all |eig(N)| <= sqrt(3)*||S||_F < 2*||S||_F  => M = N+sI is PD,
    // top eigvec of M == Horn's quaternion.
    float fro2 = Sxx*Sxx + Sxy*Sxy + Sxz*Sxz
               + Syx*Syx + Syy*Syy + Syz*Syz
               + Szx*Szx + Szy*Szy + Szz*Szz;
    float s = 2.0f * sqrtf(fro2) + 1e-30f;

    float m00 = n00 + s, m01 = n01, m02 = n02, m03 = n03;
    float m11 = n11 + s, m12 = n12, m13 = n13;
    float m22 = n22 + s, m23 = n23;
    float m33 = n33 + s;

    {
        float inv = 1.0f / (m00 + m11 + m22 + m33);
        m00 *= inv; m01 *= inv; m02 *= inv; m03 *= inv;
        m11 *= inv; m12 *= inv; m13 *= inv;
        m22 *= inv; m23 *= inv;
        m33 *= inv;
    }

    // 16 symmetric squarings with trace renormalization: M^(2^16) -> c*v*v^T.
#pragma unroll
    for (int it = 0; it < 16; ++it) {
        float p00 = m00*m00 + m01*m01 + m02*m02 + m03*m03;
        float p01 = m00*m01 + m01*m11 + m02*m12 + m03*m13;
        float p02 = m00*m02 + m01*m12 + m02*m22 + m03*m23;
        float p03 = m00*m03 + m01*m13 + m02*m23 + m03*m33;
        float p11 = m01*m01 + m11*m11 + m12*m12 + m13*m13;
        float p12 = m01*m02 + m11*m12 + m12*m22 + m13*m23;
        float p13 = m01*m03 + m11*m13 + m12*m23 + m13*m33;
        float p22 = m02*m02 + m12*m12 + m22*m22 + m23*m23;
        float p23 = m02*m03 + m12*m13 + m22*m23 + m23*m33;
        float p33 = m03*m03 + m13*m13 + m23*m23 + m33*m33;
        float inv = 1.0f / (p00 + p11 + p22 + p33);
        m00 = p00 * inv; m01 = p01 * inv; m02 = p02 * inv; m03 = p03 * inv;
        m11 = p11 * inv; m12 = p12 * inv; m13 = p13 * inv;
        m22 = p22 * inv; m23 = p23 * inv;
        m33 = p33 * inv;
    }

    // Column with the largest diagonal entry == top eigenvector.
    float qw = m00, qx = m01, qy = m02, qz = m03, best = m00;
    {
        bool g = m11 > best;
        qw = g ? m01 : qw; qx = g ? m11 : qx; qy = g ? m12 : qy; qz = g ? m13 : qz;
        best = g ? m11 : best;
        g = m22 > best;
        qw = g ? m02 : qw; qx = g ? m12 : qx; qy = g ? m22 : qy; qz = g ? m23 : qz;
        best = g ? m22 : best;
        g = m33 > best;
        qw = g ? m03 : qw; qx = g ? m13 : qx; qy = g ? m23 : qy; qz = g ? m33 : qz;
    }
    {
        float inv = rsqrtf(qw*qw + qx*qx + qy*qy + qz*qz);
        qw *= inv; qx *= inv; qy *= inv; qz *= inv;
    }

    // Quaternion -> rotation matrix (R d1 ~= d2), row-major 3x3
    float xx = qx*qx, yy = qy*qy, zz = qz*qz;
    float xy = qx*qy, xz = qx*qz, yz = qy*qz;
    float wx = qw*qx, wy = qw*qy, wz = qw*qz;

    float o0 = 1.f - 2.f*(yy + zz);
    float o1 = 2.f*(xy - wz);
    float o2 = 2.f*(xz + wy);
    float o3 = 2.f*(xy + wz);
    float o4 = 1.f - 2.f*(xx + zz);
    float o5 = 2.f*(yz - wx);
    float o6 = 2.f*(xz - wy);
    float o7 = 2.f*(yz + wx);
    float o8 = 1.f - 2.f*(xx + yy);

    // Split the 9 stores across the 4 lanes (static-index selects only).
    float* op = out + (size_t)v * 9;
    float w0 = (u == 0) ? o0 : (u == 1) ? o1 : (u == 2) ? o2 : o3;
    float w1 = (u == 0) ? o4 : (u == 1) ? o5 : (u == 2) ? o6 : o7;
    op[u]     = w0;
    op[4 + u] = w1;
    if (u == 0) op[8] = o8;
}

extern "C" void kernel_launch(void* const* d_in, const int* in_sizes, int n_in,
                              void* d_out, int out_size, void* d_ws, size_t ws_size,
                              hipStream_t stream) {
    const float* xyz1 = (const float*)d_in[0];
    const float* xyz2 = (const float*)d_in[1];
    const int*   nbr  = (const int*)  d_in[2];
    const int*   num  = (const int*)  d_in[3];
    const int*   acc  = (const int*)  d_in[4];
    const float* wgt  = (const float*)d_in[5];
    float* out = (float*)d_out;

    int N = in_sizes[3];               // numNeighbors has N entries
    int B = in_sizes[0] / (N * 3);     // xyz1 is [B,N,3]
    int total4 = B * N * 4;

    // NOTE: d_ws intentionally unused this round — isolating whether the
    // 256-MiB workspace poison fills dominate dur_us.
    (void)d_ws; (void)ws_size;

    int block = 256;
    int grid = (total4 + block - 1) / block;
    arap_rot_kernel<<<grid, block, 0, stream>>>(xyz1, xyz2, nbr, num, acc, wgt,
                                                out, B, N);
}